// Round 5
// baseline (360.984 us; speedup 1.0000x reference)
//
#include <hip/hip_runtime.h>
#include <hip/hip_cooperative_groups.h>

namespace cgx = cooperative_groups;

// Problem constants (match reference)
#define B 512
#define D 512
#define NC 100000
#define BETA 0.1f
#define MARGIN 50.0f
#define GRID 512
#define TPB 256
#define N4 (NC * D / 4)        // 12,800,000 float4 elements to copy
#define C0 3600000             // copy chunk boundaries (f4 units)
#define C1 6400000
#define C2 10000000

typedef float f4 __attribute__((ext_vector_type(4)));

// dst is only 4B-aligned (out+1) -> scalar stores; 8-deep to keep HBM saturated
__device__ __forceinline__ void copy_chunk(const f4* __restrict__ src, float* __restrict__ dst,
                                           int lo, int hi, int widx, int wstride)
{
    int i = lo + widx;
    for (; i + 7 * wstride < hi; i += 8 * wstride) {
        f4 v[8];
        #pragma unroll
        for (int u = 0; u < 8; ++u) v[u] = __builtin_nontemporal_load(&src[i + u * wstride]);
        #pragma unroll
        for (int u = 0; u < 8; ++u) {
            float* d = dst + 4 * (size_t)(i + u * wstride);
            __builtin_nontemporal_store(v[u].x, d + 0);
            __builtin_nontemporal_store(v[u].y, d + 1);
            __builtin_nontemporal_store(v[u].z, d + 2);
            __builtin_nontemporal_store(v[u].w, d + 3);
        }
    }
    for (; i < hi; i += wstride) {
        f4 v = __builtin_nontemporal_load(&src[i]);
        float* d = dst + 4 * (size_t)i;
        __builtin_nontemporal_store(v.x, d + 0);
        __builtin_nontemporal_store(v.y, d + 1);
        __builtin_nontemporal_store(v.z, d + 2);
        __builtin_nontemporal_store(v.w, d + 3);
    }
}

__global__ __launch_bounds__(TPB, 2) void k_mega(
    const float* __restrict__ features, const int* __restrict__ labels,
    const float* __restrict__ centers, float* __restrict__ out, float* __restrict__ outC,
    float* __restrict__ cgbuf, float* __restrict__ dist, float* __restrict__ Wm,
    float* __restrict__ rowLoss, float* __restrict__ rowS, float* __restrict__ rowCnt,
    int* __restrict__ winner)
{
    cgx::grid_group grid = cgx::this_grid();
    const int b = blockIdx.x, t = threadIdx.x;
    const int gid = b * TPB + t;
    const f4* src4 = (const f4*)centers;

    __shared__ float red[TPB];
    __shared__ int labs[B];       // persists across phases
    __shared__ int wsh;
    __shared__ float fsh;
    __shared__ float As[16][33];  // reused: P1 A-tile / P3 W-tile
    __shared__ float Bs[16][33];  // reused: P1 B-tile / P3 cg-tile

    labs[t] = labels[t];
    labs[t + 256] = labels[t + 256];
    if (t == 0) wsh = 1;
    __syncthreads();

    // ---------------- Phase 0: gather cg + loss partial + winner; copy chunk 0 ----------------
    {
        const int i = b;                 // GRID == B
        const int li = labs[i];
        const float2* crow = (const float2*)(centers + (size_t)li * D);
        const float2* frow = (const float2*)(features + (size_t)i * D);
        float2 c = crow[t], f = frow[t];
        ((float2*)(cgbuf + (size_t)i * D))[t] = c;
        float dx = c.x - f.x, dy = c.y - f.y;
        red[t] = fminf(fmaxf(dx * dx, 1e-12f), 1e12f) + fminf(fmaxf(dy * dy, 1e-12f), 1e12f);
        // winner[i] = 1 iff no later row shares the label (numpy scatter last-write-wins)
        for (int j = i + 1 + t; j < B; j += TPB)
            if (labs[j] == li) wsh = 0;           // benign race, same value
        __syncthreads();
        for (int s = 128; s; s >>= 1) { if (t < s) red[t] += red[t + s]; __syncthreads(); }
        if (t == 0) { rowLoss[i] = red[0]; winner[i] = wsh; }
    }
    copy_chunk(src4, outC, 0, C0, gid, GRID * TPB);
    grid.sync();

    // ---------------- Phase 1: pairwise dist (256 tiles 32x32) | copy chunk 1 ----------------
    if (b < 256) {
        const int bi = b >> 4, bj = b & 15;
        const int tx = t & 15, ty = t >> 4;
        float a00 = 0.f, a01 = 0.f, a10 = 0.f, a11 = 0.f;
        for (int k0 = 0; k0 < D; k0 += 16) {
            #pragma unroll
            for (int it = 0; it < 2; ++it) {
                int idx = t + it * 256;              // 0..511
                int r = idx >> 4, kk = idx & 15;
                As[kk][r] = cgbuf[(size_t)(bi * 32 + r) * D + k0 + kk];
                Bs[kk][r] = cgbuf[(size_t)(bj * 32 + r) * D + k0 + kk];
            }
            __syncthreads();
            #pragma unroll
            for (int kk = 0; kk < 16; ++kk) {
                float x0 = As[kk][ty * 2], x1 = As[kk][ty * 2 + 1];
                float y0 = Bs[kk][tx * 2], y1 = Bs[kk][tx * 2 + 1];
                float d00 = x0 - y0, d01 = x0 - y1, d10 = x1 - y0, d11 = x1 - y1;
                a00 += d00 * d00; a01 += d01 * d01; a10 += d10 * d10; a11 += d11 * d11;
            }
            __syncthreads();
        }
        int r0 = bi * 32 + ty * 2, c0 = bj * 32 + tx * 2;
        dist[r0 * B + c0]           = sqrtf(a00);
        dist[r0 * B + c0 + 1]       = sqrtf(a01);
        dist[(r0 + 1) * B + c0]     = sqrtf(a10);
        dist[(r0 + 1) * B + c0 + 1] = sqrtf(a11);
    } else {
        copy_chunk(src4, outC, C0, C1, (b - 256) * TPB + t, 256 * TPB);
    }
    grid.sync();

    // ---------------- Phase 2: masked softmax per row; copy chunk 2 ----------------
    {
        const int i = b;
        const int li = labs[i];
        float d0 = dist[i * B + t], d1 = dist[i * B + t + 256];
        int m0 = (labs[t] != li) && (d0 <= MARGIN);
        int m1 = (labs[t + 256] != li) && (d1 <= MARGIN);
        red[t] = fmaxf(m0 ? d0 : 0.f, m1 ? d1 : 0.f); __syncthreads();
        for (int s = 128; s; s >>= 1) { if (t < s) red[t] = fmaxf(red[t], red[t + s]); __syncthreads(); }
        float maxd = red[0]; __syncthreads();
        float n0 = m0 ? expf(maxd - d0) : 0.f;
        float n1 = m1 ? expf(maxd - d1) : 0.f;
        red[t] = n0 + n1; __syncthreads();
        for (int s = 128; s; s >>= 1) { if (t < s) red[t] += red[t + s]; __syncthreads(); }
        float Z = red[0] + 1e-6f; __syncthreads();
        float invZ = 1.f / Z;
        Wm[i * B + t]       = n0 * invZ;
        Wm[i * B + t + 256] = n1 * invZ;
        red[t] = (float)(m0 + m1); __syncthreads();
        for (int s = 128; s; s >>= 1) { if (t < s) red[t] += red[t + s]; __syncthreads(); }
        if (t == 0) { rowS[i] = (Z - 1e-6f) * invZ; rowCnt[i] = red[0]; }
        __syncthreads();
    }
    copy_chunk(src4, outC, C1, C2, gid, GRID * TPB);
    grid.sync();

    // ---------------- Phase 3: delta2 GEMM (values -> registers) | loss | copy chunk 3 ----------------
    float val00 = 0.f, val01 = 0.f, val10 = 0.f, val11 = 0.f;
    size_t orow0 = 0, orow1 = 0;
    int wn0 = 0, wn1 = 0, dcol = 0;
    if (b < 256) {
        // per-block flag = (sum(mask) >= 1)
        red[t] = rowCnt[t] + rowCnt[t + 256]; __syncthreads();
        for (int s = 128; s; s >>= 1) { if (t < s) red[t] += red[t + s]; __syncthreads(); }
        if (t == 0) fsh = (red[0] < 1.0f) ? 0.f : 1.f;
        __syncthreads();
        const float flagv = fsh;
        const int bi = b >> 4, bj = b & 15;
        const int tx = t & 15, ty = t >> 4;
        float a00 = 0.f, a01 = 0.f, a10 = 0.f, a11 = 0.f;
        for (int j0 = 0; j0 < B; j0 += 16) {
            #pragma unroll
            for (int it = 0; it < 2; ++it) {
                int idx = t + it * 256;
                int r = idx >> 4, jj = idx & 15;
                As[jj][r] = Wm[(size_t)(bi * 32 + r) * B + j0 + jj];
                int c = idx & 31, jj2 = idx >> 5;
                Bs[jj2][c] = cgbuf[(size_t)(j0 + jj2) * D + bj * 32 + c];
            }
            __syncthreads();
            #pragma unroll
            for (int kk = 0; kk < 16; ++kk) {
                float w0 = As[kk][ty * 2], w1 = As[kk][ty * 2 + 1];
                float c0 = Bs[kk][tx * 2], c1 = Bs[kk][tx * 2 + 1];
                a00 += w0 * c0; a01 += w0 * c1; a10 += w1 * c0; a11 += w1 * c1;
            }
            __syncthreads();
        }
        int i0 = bi * 32 + ty * 2, i1 = i0 + 1;
        dcol = bj * 32 + tx * 2;
        float s0 = rowS[i0], s1 = rowS[i1];
        wn0 = winner[i0]; wn1 = winner[i1];
        orow0 = (size_t)labs[i0] * D; orow1 = (size_t)labs[i1] * D;
        {
            float c = cgbuf[(size_t)i0 * D + dcol], f = features[(size_t)i0 * D + dcol];
            val00 = 0.5f * (c + f) - BETA * flagv * (s0 * c - a00);
            c = cgbuf[(size_t)i0 * D + dcol + 1]; f = features[(size_t)i0 * D + dcol + 1];
            val01 = 0.5f * (c + f) - BETA * flagv * (s0 * c - a01);
            c = cgbuf[(size_t)i1 * D + dcol]; f = features[(size_t)i1 * D + dcol];
            val10 = 0.5f * (c + f) - BETA * flagv * (s1 * c - a10);
            c = cgbuf[(size_t)i1 * D + dcol + 1]; f = features[(size_t)i1 * D + dcol + 1];
            val11 = 0.5f * (c + f) - BETA * flagv * (s1 * c - a11);
        }
    } else {
        if (b == 256) {
            red[t] = rowLoss[t] + rowLoss[t + 256]; __syncthreads();
            for (int s = 128; s; s >>= 1) { if (t < s) red[t] += red[t + s]; __syncthreads(); }
            if (t == 0) out[0] = red[0] * (1.0f / ((float)B * (float)D));
        }
        copy_chunk(src4, outC, C2, N4, (b - 256) * TPB + t, 256 * TPB);
    }
    grid.sync();

    // ---------------- Phase 4: scatter winner rows (after ALL copying done) ----------------
    if (b < 256) {
        if (wn0) { outC[orow0 + dcol] = val00; outC[orow0 + dcol + 1] = val01; }
        if (wn1) { outC[orow1 + dcol] = val10; outC[orow1 + dcol + 1] = val11; }
    }
}

extern "C" void kernel_launch(void* const* d_in, const int* in_sizes, int n_in,
                              void* d_out, int out_size, void* d_ws, size_t ws_size,
                              hipStream_t stream)
{
    const float* features = (const float*)d_in[0];
    const int*   labels   = (const int*)d_in[1];
    const float* centers  = (const float*)d_in[2];

    float* out  = (float*)d_out;     // out[0] = loss, out[1..] = new_centers
    float* outC = out + 1;

    char* ws = (char*)d_ws;
    float* cgbuf   = (float*)(ws);                 // 1 MB
    float* dist    = (float*)(ws + 1048576);       // 1 MB
    float* Wm      = (float*)(ws + 2097152);       // 1 MB
    float* rowLoss = (float*)(ws + 3145728);       // 2 KB
    float* rowS    = (float*)(ws + 3147776);       // 2 KB
    float* rowCnt  = (float*)(ws + 3149824);       // 2 KB
    int*   winner  = (int*)  (ws + 3151872);       // 2 KB

    void* args[] = {(void*)&features, (void*)&labels, (void*)&centers, (void*)&out,
                    (void*)&outC, (void*)&cgbuf, (void*)&dist, (void*)&Wm,
                    (void*)&rowLoss, (void*)&rowS, (void*)&rowCnt, (void*)&winner};
    hipLaunchCooperativeKernel((const void*)k_mega, dim3(GRID), dim3(TPB), args, 0, stream);
}

// Round 7
// 125.281 us; speedup vs baseline: 2.8814x; 2.8814x over previous
//
#include <hip/hip_runtime.h>

// Problem constants (match reference)
#define B 512
#define D 512
#define NC 100000
#define BETA 0.1f
#define MARGIN 50.0f
#define TPB 256
#define N4 (NC * D / 4)        // 12,800,000 float4 elements to copy
#define C0 4266666             // copy chunk boundaries (f4 units)
#define C1 8533332

typedef float f4 __attribute__((ext_vector_type(4)));

// dst is only 4B-aligned (out+1) -> scalar stores; 8-deep to keep HBM saturated
__device__ __forceinline__ void copy_chunk(const f4* __restrict__ src, float* __restrict__ dst,
                                           int lo, int hi, int widx, int wstride)
{
    int i = lo + widx;
    for (; i + 7 * wstride < hi; i += 8 * wstride) {
        f4 v[8];
        #pragma unroll
        for (int u = 0; u < 8; ++u) v[u] = __builtin_nontemporal_load(&src[i + u * wstride]);
        #pragma unroll
        for (int u = 0; u < 8; ++u) {
            float* d = dst + 4 * (size_t)(i + u * wstride);
            __builtin_nontemporal_store(v[u].x, d + 0);
            __builtin_nontemporal_store(v[u].y, d + 1);
            __builtin_nontemporal_store(v[u].z, d + 2);
            __builtin_nontemporal_store(v[u].w, d + 3);
        }
    }
    for (; i < hi; i += wstride) {
        f4 v = __builtin_nontemporal_load(&src[i]);
        float* d = dst + 4 * (size_t)i;
        __builtin_nontemporal_store(v.x, d + 0);
        __builtin_nontemporal_store(v.y, d + 1);
        __builtin_nontemporal_store(v.z, d + 2);
        __builtin_nontemporal_store(v.w, d + 3);
    }
}

// ---- k0: blocks 0-511 gather cg + loss partial + winner; blocks 512-2047 copy chunk0 ----
__global__ __launch_bounds__(TPB) void k0_gather(
    const float* __restrict__ centers, const float* __restrict__ features,
    const int* __restrict__ labels, float* __restrict__ cgbuf,
    float* __restrict__ rowLoss, int* __restrict__ winner, float* __restrict__ outC)
{
    const int b = blockIdx.x, t = threadIdx.x;
    if (b < B) {
        __shared__ float red[TPB];
        __shared__ int labs[B];
        __shared__ int wsh;
        labs[t] = labels[t]; labs[t + 256] = labels[t + 256];
        if (t == 0) wsh = 1;
        __syncthreads();
        const int i = b;
        const int li = labs[i];
        const float2* crow = (const float2*)(centers + (size_t)li * D);
        const float2* frow = (const float2*)(features + (size_t)i * D);
        float2 c = crow[t], f = frow[t];
        ((float2*)(cgbuf + (size_t)i * D))[t] = c;
        float dx = c.x - f.x, dy = c.y - f.y;
        red[t] = fminf(fmaxf(dx * dx, 1e-12f), 1e12f) + fminf(fmaxf(dy * dy, 1e-12f), 1e12f);
        for (int j = i + 1 + t; j < B; j += TPB)
            if (labs[j] == li) wsh = 0;           // benign race, same value
        __syncthreads();
        for (int s = 128; s; s >>= 1) { if (t < s) red[t] += red[t + s]; __syncthreads(); }
        if (t == 0) { rowLoss[i] = red[0]; winner[i] = wsh; }
    } else {
        copy_chunk((const f4*)centers, outC, 0, C0, (b - 512) * TPB + t, 1536 * TPB);
    }
}

// ---- k1: blocks 0-255 pairwise dist (32x32 tiles); blocks 256-2047 copy chunk1 ----
__global__ __launch_bounds__(TPB) void k1_pairdist(
    const float* __restrict__ centers, const float* __restrict__ cgbuf,
    float* __restrict__ dist, float* __restrict__ outC)
{
    const int b = blockIdx.x, t = threadIdx.x;
    if (b < 256) {
        __shared__ float As[16][33];
        __shared__ float Bs[16][33];
        const int bi = b >> 4, bj = b & 15;
        const int tx = t & 15, ty = t >> 4;
        float a00 = 0.f, a01 = 0.f, a10 = 0.f, a11 = 0.f;
        for (int k0 = 0; k0 < D; k0 += 16) {
            #pragma unroll
            for (int it = 0; it < 2; ++it) {
                int idx = t + it * 256;              // 0..511
                int r = idx >> 4, kk = idx & 15;
                As[kk][r] = cgbuf[(size_t)(bi * 32 + r) * D + k0 + kk];
                Bs[kk][r] = cgbuf[(size_t)(bj * 32 + r) * D + k0 + kk];
            }
            __syncthreads();
            #pragma unroll
            for (int kk = 0; kk < 16; ++kk) {
                float x0 = As[kk][ty * 2], x1 = As[kk][ty * 2 + 1];
                float y0 = Bs[kk][tx * 2], y1 = Bs[kk][tx * 2 + 1];
                float d00 = x0 - y0, d01 = x0 - y1, d10 = x1 - y0, d11 = x1 - y1;
                a00 += d00 * d00; a01 += d01 * d01; a10 += d10 * d10; a11 += d11 * d11;
            }
            __syncthreads();
        }
        int r0 = bi * 32 + ty * 2, c0 = bj * 32 + tx * 2;
        dist[r0 * B + c0]           = sqrtf(a00);
        dist[r0 * B + c0 + 1]       = sqrtf(a01);
        dist[(r0 + 1) * B + c0]     = sqrtf(a10);
        dist[(r0 + 1) * B + c0 + 1] = sqrtf(a11);
    } else {
        copy_chunk((const f4*)centers, outC, C0, C1, (b - 256) * TPB + t, 1792 * TPB);
    }
}

// ---- k2: blocks 0-511 masked softmax per row; blocks 512-2047 copy chunk2 (final) ----
__global__ __launch_bounds__(TPB) void k2_softmax(
    const float* __restrict__ centers, const float* __restrict__ dist,
    const int* __restrict__ labels, float* __restrict__ Wm,
    float* __restrict__ rowS, float* __restrict__ rowCnt, float* __restrict__ outC)
{
    const int b = blockIdx.x, t = threadIdx.x;
    if (b < B) {
        __shared__ float red[TPB];
        __shared__ int labs[B];
        labs[t] = labels[t]; labs[t + 256] = labels[t + 256];
        __syncthreads();
        const int i = b;
        const int li = labs[i];
        float d0 = dist[i * B + t], d1 = dist[i * B + t + 256];
        int m0 = (labs[t] != li) && (d0 <= MARGIN);
        int m1 = (labs[t + 256] != li) && (d1 <= MARGIN);
        red[t] = fmaxf(m0 ? d0 : 0.f, m1 ? d1 : 0.f); __syncthreads();
        for (int s = 128; s; s >>= 1) { if (t < s) red[t] = fmaxf(red[t], red[t + s]); __syncthreads(); }
        float maxd = red[0]; __syncthreads();
        float n0 = m0 ? expf(maxd - d0) : 0.f;
        float n1 = m1 ? expf(maxd - d1) : 0.f;
        red[t] = n0 + n1; __syncthreads();
        for (int s = 128; s; s >>= 1) { if (t < s) red[t] += red[t + s]; __syncthreads(); }
        float Z = red[0] + 1e-6f; __syncthreads();
        float invZ = 1.f / Z;
        Wm[i * B + t]       = n0 * invZ;
        Wm[i * B + t + 256] = n1 * invZ;
        red[t] = (float)(m0 + m1); __syncthreads();
        for (int s = 128; s; s >>= 1) { if (t < s) red[t] += red[t + s]; __syncthreads(); }
        if (t == 0) { rowS[i] = (Z - 1e-6f) * invZ; rowCnt[i] = red[0]; }
    } else {
        copy_chunk((const f4*)centers, outC, C1, N4, (b - 512) * TPB + t, 1536 * TPB);
    }
}

// ---- k3: blocks 0-255 delta2 GEMM + epilogue + scatter; block 256 loss ----
__global__ __launch_bounds__(TPB) void k3_final(
    const float* __restrict__ features, const int* __restrict__ labels,
    const float* __restrict__ cgbuf, const float* __restrict__ Wm,
    const float* __restrict__ rowS, const float* __restrict__ rowCnt,
    const int* __restrict__ winner, const float* __restrict__ rowLoss,
    float* __restrict__ out, float* __restrict__ outC)
{
    const int b = blockIdx.x, t = threadIdx.x;
    __shared__ float red[TPB];
    if (b < 256) {
        __shared__ float As[16][33];
        __shared__ float Bs[16][33];
        __shared__ float fsh;
        // flag = (sum of all rowCnt >= 1), recomputed per block
        red[t] = rowCnt[t] + rowCnt[t + 256]; __syncthreads();
        for (int s = 128; s; s >>= 1) { if (t < s) red[t] += red[t + s]; __syncthreads(); }
        if (t == 0) fsh = (red[0] < 1.0f) ? 0.f : 1.f;
        __syncthreads();
        const float flagv = fsh;
        const int bi = b >> 4, bj = b & 15;
        const int tx = t & 15, ty = t >> 4;
        float a00 = 0.f, a01 = 0.f, a10 = 0.f, a11 = 0.f;
        for (int j0 = 0; j0 < B; j0 += 16) {
            #pragma unroll
            for (int it = 0; it < 2; ++it) {
                int idx = t + it * 256;
                int r = idx >> 4, jj = idx & 15;
                As[jj][r] = Wm[(size_t)(bi * 32 + r) * B + j0 + jj];
                int c = idx & 31, jj2 = idx >> 5;
                Bs[jj2][c] = cgbuf[(size_t)(j0 + jj2) * D + bj * 32 + c];
            }
            __syncthreads();
            #pragma unroll
            for (int kk = 0; kk < 16; ++kk) {
                float w0 = As[kk][ty * 2], w1 = As[kk][ty * 2 + 1];
                float c0 = Bs[kk][tx * 2], c1 = Bs[kk][tx * 2 + 1];
                a00 += w0 * c0; a01 += w0 * c1; a10 += w1 * c0; a11 += w1 * c1;
            }
            __syncthreads();
        }
        const int i0 = bi * 32 + ty * 2, i1 = i0 + 1;
        const int dcol = bj * 32 + tx * 2;
        float s0 = rowS[i0], s1 = rowS[i1];
        int wn0 = winner[i0], wn1 = winner[i1];
        size_t orow0 = (size_t)labels[i0] * D, orow1 = (size_t)labels[i1] * D;
        float c, f;
        c = cgbuf[(size_t)i0 * D + dcol];     f = features[(size_t)i0 * D + dcol];
        float val00 = 0.5f * (c + f) - BETA * flagv * (s0 * c - a00);
        c = cgbuf[(size_t)i0 * D + dcol + 1]; f = features[(size_t)i0 * D + dcol + 1];
        float val01 = 0.5f * (c + f) - BETA * flagv * (s0 * c - a01);
        c = cgbuf[(size_t)i1 * D + dcol];     f = features[(size_t)i1 * D + dcol];
        float val10 = 0.5f * (c + f) - BETA * flagv * (s1 * c - a10);
        c = cgbuf[(size_t)i1 * D + dcol + 1]; f = features[(size_t)i1 * D + dcol + 1];
        float val11 = 0.5f * (c + f) - BETA * flagv * (s1 * c - a11);
        if (wn0) { outC[orow0 + dcol] = val00; outC[orow0 + dcol + 1] = val01; }
        if (wn1) { outC[orow1 + dcol] = val10; outC[orow1 + dcol + 1] = val11; }
    } else {
        red[t] = rowLoss[t] + rowLoss[t + 256]; __syncthreads();
        for (int s = 128; s; s >>= 1) { if (t < s) red[t] += red[t + s]; __syncthreads(); }
        if (t == 0) out[0] = red[0] * (1.0f / ((float)B * (float)D));
    }
}

extern "C" void kernel_launch(void* const* d_in, const int* in_sizes, int n_in,
                              void* d_out, int out_size, void* d_ws, size_t ws_size,
                              hipStream_t stream)
{
    const float* features = (const float*)d_in[0];
    const int*   labels   = (const int*)d_in[1];
    const float* centers  = (const float*)d_in[2];

    float* out  = (float*)d_out;     // out[0] = loss, out[1..] = new_centers
    float* outC = out + 1;

    char* ws = (char*)d_ws;
    float* cgbuf   = (float*)(ws);                 // 1 MB
    float* dist    = (float*)(ws + 1048576);       // 1 MB
    float* Wm      = (float*)(ws + 2097152);       // 1 MB
    float* rowLoss = (float*)(ws + 3145728);       // 2 KB
    float* rowS    = (float*)(ws + 3147776);       // 2 KB
    float* rowCnt  = (float*)(ws + 3149824);       // 2 KB
    int*   winner  = (int*)  (ws + 3151872);       // 2 KB

    k0_gather<<<2048, TPB, 0, stream>>>(centers, features, labels, cgbuf, rowLoss, winner, outC);
    k1_pairdist<<<2048, TPB, 0, stream>>>(centers, cgbuf, dist, outC);
    k2_softmax<<<2048, TPB, 0, stream>>>(centers, dist, labels, Wm, rowS, rowCnt, outC);
    k3_final<<<257, TPB, 0, stream>>>(features, labels, cgbuf, Wm, rowS, rowCnt,
                                      winner, rowLoss, out, outC);
}

// Round 8
// 102.533 us; speedup vs baseline: 3.5207x; 1.2219x over previous
//
#include <hip/hip_runtime.h>

// Problem constants (match reference)
#define B 512
#define D 512
#define NC 100000
#define BETA 0.1f
#define MARGIN 50.0f
#define TPB 256
#define NFLOAT (NC * D)            // 51,200,000 floats to copy
// f4-group k covers float indices [3+4k, 7+4k); dst out+1+3 = out+4 is 16B-aligned
#define N4V 12799999               // number of f4 groups (float idx 3 .. 51,199,998)
// chunk boundaries over [0, N4V), sized ~proportional to copy-worker counts 1536/1792/1536/1791
#define K0E 2954290
#define K1E 6400962
#define K2E 9355252

typedef float f4 __attribute__((ext_vector_type(4)));

// Copy f4 groups [lo,hi): dense aligned nontemporal f4 stores to dst+3 (16B-aligned),
// 4B-aligned dwordx4 loads from src+3 (plain/cached: centers stays L3-resident).
__device__ __forceinline__ void copy_shifted(const float* __restrict__ srcF, float* __restrict__ dstF,
                                             int lo, int hi, int widx, int wstride)
{
    const float* s = srcF + 3;
    f4* d = (f4*)(dstF + 3);
    int i = lo + widx;
    for (; i + 7 * wstride < hi; i += 8 * wstride) {
        f4 v[8];
        #pragma unroll
        for (int u = 0; u < 8; ++u) __builtin_memcpy(&v[u], s + 4 * (size_t)(i + u * wstride), 16);
        #pragma unroll
        for (int u = 0; u < 8; ++u) __builtin_nontemporal_store(v[u], d + (i + u * wstride));
    }
    for (; i < hi; i += wstride) {
        f4 v;
        __builtin_memcpy(&v, s + 4 * (size_t)i, 16);
        __builtin_nontemporal_store(v, d + i);
    }
}

// ---- k0: blocks 0-511 gather cg + loss partial + winner; blocks 512-2047 copy chunk0 ----
__global__ __launch_bounds__(TPB) void k0_gather(
    const float* __restrict__ centers, const float* __restrict__ features,
    const int* __restrict__ labels, float* __restrict__ cgbuf,
    float* __restrict__ rowLoss, int* __restrict__ winner, float* __restrict__ outC)
{
    const int b = blockIdx.x, t = threadIdx.x;
    if (b < B) {
        __shared__ float red[TPB];
        __shared__ int labs[B];
        __shared__ int wsh;
        labs[t] = labels[t]; labs[t + 256] = labels[t + 256];
        if (t == 0) wsh = 1;
        __syncthreads();
        const int i = b;
        const int li = labs[i];
        const float2* crow = (const float2*)(centers + (size_t)li * D);
        const float2* frow = (const float2*)(features + (size_t)i * D);
        float2 c = crow[t], f = frow[t];
        ((float2*)(cgbuf + (size_t)i * D))[t] = c;
        float dx = c.x - f.x, dy = c.y - f.y;
        red[t] = fminf(fmaxf(dx * dx, 1e-12f), 1e12f) + fminf(fmaxf(dy * dy, 1e-12f), 1e12f);
        for (int j = i + 1 + t; j < B; j += TPB)
            if (labs[j] == li) wsh = 0;           // benign race, same value
        __syncthreads();
        for (int s = 128; s; s >>= 1) { if (t < s) red[t] += red[t + s]; __syncthreads(); }
        if (t == 0) { rowLoss[i] = red[0]; winner[i] = wsh; }
    } else {
        copy_shifted(centers, outC, 0, K0E, (b - 512) * TPB + t, 1536 * TPB);
    }
}

// ---- k1: blocks 0-255 pairwise dist (32x32 tiles); blocks 256-2047 copy chunk1 ----
__global__ __launch_bounds__(TPB) void k1_pairdist(
    const float* __restrict__ centers, const float* __restrict__ cgbuf,
    float* __restrict__ dist, float* __restrict__ outC)
{
    const int b = blockIdx.x, t = threadIdx.x;
    if (b < 256) {
        __shared__ float As[16][33];
        __shared__ float Bs[16][33];
        const int bi = b >> 4, bj = b & 15;
        const int tx = t & 15, ty = t >> 4;
        float a00 = 0.f, a01 = 0.f, a10 = 0.f, a11 = 0.f;
        for (int k0 = 0; k0 < D; k0 += 16) {
            #pragma unroll
            for (int it = 0; it < 2; ++it) {
                int idx = t + it * 256;              // 0..511
                int r = idx >> 4, kk = idx & 15;
                As[kk][r] = cgbuf[(size_t)(bi * 32 + r) * D + k0 + kk];
                Bs[kk][r] = cgbuf[(size_t)(bj * 32 + r) * D + k0 + kk];
            }
            __syncthreads();
            #pragma unroll
            for (int kk = 0; kk < 16; ++kk) {
                float x0 = As[kk][ty * 2], x1 = As[kk][ty * 2 + 1];
                float y0 = Bs[kk][tx * 2], y1 = Bs[kk][tx * 2 + 1];
                float d00 = x0 - y0, d01 = x0 - y1, d10 = x1 - y0, d11 = x1 - y1;
                a00 += d00 * d00; a01 += d01 * d01; a10 += d10 * d10; a11 += d11 * d11;
            }
            __syncthreads();
        }
        int r0 = bi * 32 + ty * 2, c0 = bj * 32 + tx * 2;
        dist[r0 * B + c0]           = sqrtf(a00);
        dist[r0 * B + c0 + 1]       = sqrtf(a01);
        dist[(r0 + 1) * B + c0]     = sqrtf(a10);
        dist[(r0 + 1) * B + c0 + 1] = sqrtf(a11);
    } else {
        copy_shifted(centers, outC, K0E, K1E, (b - 256) * TPB + t, 1792 * TPB);
    }
}

// ---- k2: blocks 0-511 masked softmax per row; blocks 512-2047 copy chunk2 ----
__global__ __launch_bounds__(TPB) void k2_softmax(
    const float* __restrict__ centers, const float* __restrict__ dist,
    const int* __restrict__ labels, float* __restrict__ Wm,
    float* __restrict__ rowS, float* __restrict__ rowCnt, float* __restrict__ outC)
{
    const int b = blockIdx.x, t = threadIdx.x;
    if (b < B) {
        __shared__ float red[TPB];
        __shared__ int labs[B];
        labs[t] = labels[t]; labs[t + 256] = labels[t + 256];
        __syncthreads();
        const int i = b;
        const int li = labs[i];
        float d0 = dist[i * B + t], d1 = dist[i * B + t + 256];
        int m0 = (labs[t] != li) && (d0 <= MARGIN);
        int m1 = (labs[t + 256] != li) && (d1 <= MARGIN);
        red[t] = fmaxf(m0 ? d0 : 0.f, m1 ? d1 : 0.f); __syncthreads();
        for (int s = 128; s; s >>= 1) { if (t < s) red[t] = fmaxf(red[t], red[t + s]); __syncthreads(); }
        float maxd = red[0]; __syncthreads();
        float n0 = m0 ? expf(maxd - d0) : 0.f;
        float n1 = m1 ? expf(maxd - d1) : 0.f;
        red[t] = n0 + n1; __syncthreads();
        for (int s = 128; s; s >>= 1) { if (t < s) red[t] += red[t + s]; __syncthreads(); }
        float Z = red[0] + 1e-6f; __syncthreads();
        float invZ = 1.f / Z;
        Wm[i * B + t]       = n0 * invZ;
        Wm[i * B + t + 256] = n1 * invZ;
        red[t] = (float)(m0 + m1); __syncthreads();
        for (int s = 128; s; s >>= 1) { if (t < s) red[t] += red[t + s]; __syncthreads(); }
        if (t == 0) { rowS[i] = (Z - 1e-6f) * invZ; rowCnt[i] = red[0]; }
    } else {
        copy_shifted(centers, outC, K1E, K2E, (b - 512) * TPB + t, 1536 * TPB);
    }
}

// ---- k3: blocks 0-255 delta2 GEMM -> vals; block 256 loss + head/tail; 257-2047 copy chunk3 ----
__global__ __launch_bounds__(TPB) void k3_gemm(
    const float* __restrict__ features, const float* __restrict__ centers,
    const float* __restrict__ cgbuf, const float* __restrict__ Wm,
    const float* __restrict__ rowS, const float* __restrict__ rowCnt,
    const float* __restrict__ rowLoss, float* __restrict__ vals,
    float* __restrict__ out, float* __restrict__ outC)
{
    const int b = blockIdx.x, t = threadIdx.x;
    if (b < 256) {
        __shared__ float red[TPB];
        __shared__ float As[16][33];
        __shared__ float Bs[16][33];
        __shared__ float fsh;
        // flag = (sum of all rowCnt >= 1), recomputed per block
        red[t] = rowCnt[t] + rowCnt[t + 256]; __syncthreads();
        for (int s = 128; s; s >>= 1) { if (t < s) red[t] += red[t + s]; __syncthreads(); }
        if (t == 0) fsh = (red[0] < 1.0f) ? 0.f : 1.f;
        __syncthreads();
        const float flagv = fsh;
        const int bi = b >> 4, bj = b & 15;
        const int tx = t & 15, ty = t >> 4;
        float a00 = 0.f, a01 = 0.f, a10 = 0.f, a11 = 0.f;
        for (int j0 = 0; j0 < B; j0 += 16) {
            #pragma unroll
            for (int it = 0; it < 2; ++it) {
                int idx = t + it * 256;
                int r = idx >> 4, jj = idx & 15;
                As[jj][r] = Wm[(size_t)(bi * 32 + r) * B + j0 + jj];
                int c = idx & 31, jj2 = idx >> 5;
                Bs[jj2][c] = cgbuf[(size_t)(j0 + jj2) * D + bj * 32 + c];
            }
            __syncthreads();
            #pragma unroll
            for (int kk = 0; kk < 16; ++kk) {
                float w0 = As[kk][ty * 2], w1 = As[kk][ty * 2 + 1];
                float c0 = Bs[kk][tx * 2], c1 = Bs[kk][tx * 2 + 1];
                a00 += w0 * c0; a01 += w0 * c1; a10 += w1 * c0; a11 += w1 * c1;
            }
            __syncthreads();
        }
        const int i0 = bi * 32 + ty * 2, i1 = i0 + 1;
        const int dcol = bj * 32 + tx * 2;
        float s0 = rowS[i0], s1 = rowS[i1];
        float c, f;
        c = cgbuf[(size_t)i0 * D + dcol];     f = features[(size_t)i0 * D + dcol];
        vals[(size_t)i0 * D + dcol]     = 0.5f * (c + f) - BETA * flagv * (s0 * c - a00);
        c = cgbuf[(size_t)i0 * D + dcol + 1]; f = features[(size_t)i0 * D + dcol + 1];
        vals[(size_t)i0 * D + dcol + 1] = 0.5f * (c + f) - BETA * flagv * (s0 * c - a01);
        c = cgbuf[(size_t)i1 * D + dcol];     f = features[(size_t)i1 * D + dcol];
        vals[(size_t)i1 * D + dcol]     = 0.5f * (c + f) - BETA * flagv * (s1 * c - a10);
        c = cgbuf[(size_t)i1 * D + dcol + 1]; f = features[(size_t)i1 * D + dcol + 1];
        vals[(size_t)i1 * D + dcol + 1] = 0.5f * (c + f) - BETA * flagv * (s1 * c - a11);
    } else if (b == 256) {
        __shared__ float red[TPB];
        red[t] = rowLoss[t] + rowLoss[t + 256]; __syncthreads();
        for (int s = 128; s; s >>= 1) { if (t < s) red[t] += red[t + s]; __syncthreads(); }
        if (t == 0) out[0] = red[0] * (1.0f / ((float)B * (float)D));
        // head (float idx 0,1,2) and tail (float idx 51,199,999) not covered by f4 grid.
        // Safe here: k4's scatter (later) overwrites if these cells belong to winner rows.
        if (t == 1) { outC[0] = centers[0]; outC[1] = centers[1]; outC[2] = centers[2]; }
        if (t == 2) { outC[NFLOAT - 1] = centers[NFLOAT - 1]; }
    } else {
        copy_shifted(centers, outC, K2E, N4V, (b - 257) * TPB + t, 1791 * TPB);
    }
}

// ---- k4: scatter winner rows from vals (runs after ALL copying complete) ----
__global__ __launch_bounds__(TPB) void k4_scatter(
    const float* __restrict__ vals, const int* __restrict__ labels,
    const int* __restrict__ winner, float* __restrict__ outC)
{
    const int b = blockIdx.x, t = threadIdx.x;
    const int i = b * 2 + (t >> 7);          // row 0..511
    const int dcol = (t & 127) * 4;
    if (!winner[i]) return;
    f4 v;
    __builtin_memcpy(&v, &vals[(size_t)i * D + dcol], 16);
    float* dst = outC + (size_t)labels[i] * D + dcol;   // 4B-aligned only
    __builtin_memcpy(dst, &v, 16);
}

extern "C" void kernel_launch(void* const* d_in, const int* in_sizes, int n_in,
                              void* d_out, int out_size, void* d_ws, size_t ws_size,
                              hipStream_t stream)
{
    const float* features = (const float*)d_in[0];
    const int*   labels   = (const int*)d_in[1];
    const float* centers  = (const float*)d_in[2];

    float* out  = (float*)d_out;     // out[0] = loss, out[1..] = new_centers
    float* outC = out + 1;

    char* ws = (char*)d_ws;
    float* cgbuf   = (float*)(ws);                 // 1 MB
    float* dist    = (float*)(ws + 1048576);       // 1 MB
    float* Wm      = (float*)(ws + 2097152);       // 1 MB
    float* vals    = (float*)(ws + 3145728);       // 1 MB
    float* rowLoss = (float*)(ws + 4194304);       // 2 KB
    float* rowS    = (float*)(ws + 4196352);       // 2 KB
    float* rowCnt  = (float*)(ws + 4198400);       // 2 KB
    int*   winner  = (int*)  (ws + 4200448);       // 2 KB

    k0_gather<<<2048, TPB, 0, stream>>>(centers, features, labels, cgbuf, rowLoss, winner, outC);
    k1_pairdist<<<2048, TPB, 0, stream>>>(centers, cgbuf, dist, outC);
    k2_softmax<<<2048, TPB, 0, stream>>>(centers, dist, labels, Wm, rowS, rowCnt, outC);
    k3_gemm<<<2048, TPB, 0, stream>>>(features, centers, cgbuf, Wm, rowS, rowCnt,
                                      rowLoss, vals, out, outC);
    k4_scatter<<<256, TPB, 0, stream>>>(vals, labels, winner, outC);
}

// Round 10
// 101.872 us; speedup vs baseline: 3.5435x; 1.0065x over previous
//
#include <hip/hip_runtime.h>

// Problem constants (match reference)
#define B 512
#define D 512
#define NC 100000
#define BETA 0.1f
#define MARGIN 50.0f
#define TPB 256
#define NFLOAT (NC * D)            // 51,200,000 floats in new_centers
// Aligned f4 groups of the OUT buffer: group g = out[4g..4g+4).
// Group 0 holds loss + centers[0..3) (handled scalar); groups [1, NG) are bulk.
// out[4g+0]=centers[4g-1]=src4[g-1].w ; out[4g+1..4]=src4[g].x/.y/.z
#define NG 12800000
// chunk boundaries over groups [1, NG), ~proportional to copy-worker counts 1536/1792/1536/1791
#define K0E 2954330
#define K1E 6401047
#define K2E 9355376

typedef float f4 __attribute__((ext_vector_type(4)));

// Copy out-groups [lo,hi): BOTH sides 16B-aligned. Each lane: 1 aligned f4 load,
// shfl_up for the previous group's .w (lane 0 patch-loads), aligned nt f4 store.
// ALL loop conditions are wave-uniform (g - lane is wave-invariant), so every lane
// executes every __shfl_up in lockstep; only loads are clamped / stores predicated.
__device__ __forceinline__ void copy_groups(const f4* __restrict__ src4, f4* __restrict__ dst4,
                                            int lo, int hi, int widx, int wstride)
{
    const int lane = widx & 63;
    int g = lo + widx;
    // main: lane63's 8th group still < hi  ->  no predication needed anywhere
    for (; (g - lane) + 63 + 7 * wstride < hi; g += 8 * wstride) {
        f4 v[8];
        #pragma unroll
        for (int u = 0; u < 8; ++u) v[u] = src4[g + u * wstride];
        float pw[8];
        #pragma unroll
        for (int u = 0; u < 8; ++u) {
            pw[u] = __shfl_up(v[u].w, 1, 64);
            if (lane == 0) pw[u] = src4[g + u * wstride - 1].w;
        }
        #pragma unroll
        for (int u = 0; u < 8; ++u) {
            f4 o = { pw[u], v[u].x, v[u].y, v[u].z };
            __builtin_nontemporal_store(o, dst4 + (g + u * wstride));
        }
    }
    // tail: uniform condition on lane0's g (max remaining); clamp loads, predicate stores
    for (; (g - lane) < hi; g += wstride) {
        int gc = (g < hi) ? g : (hi - 1);
        f4 v = src4[gc];
        float pw = __shfl_up(v.w, 1, 64);
        if (lane == 0) pw = src4[gc - 1].w;
        if (g < hi) {
            f4 o = { pw, v.x, v.y, v.z };
            __builtin_nontemporal_store(o, dst4 + g);
        }
    }
}

// ---- k0: blocks 0-511 gather cg + loss partial + winner; blocks 512-2047 copy chunk0 ----
__global__ __launch_bounds__(TPB) void k0_gather(
    const float* __restrict__ centers, const float* __restrict__ features,
    const int* __restrict__ labels, float* __restrict__ cgbuf,
    float* __restrict__ rowLoss, int* __restrict__ winner, float* __restrict__ outAll)
{
    const int b = blockIdx.x, t = threadIdx.x;
    if (b < B) {
        __shared__ float red[TPB];
        __shared__ int labs[B];
        __shared__ int wsh;
        labs[t] = labels[t]; labs[t + 256] = labels[t + 256];
        if (t == 0) wsh = 1;
        __syncthreads();
        const int i = b;
        const int li = labs[i];
        const float2* crow = (const float2*)(centers + (size_t)li * D);
        const float2* frow = (const float2*)(features + (size_t)i * D);
        float2 c = crow[t], f = frow[t];
        ((float2*)(cgbuf + (size_t)i * D))[t] = c;
        float dx = c.x - f.x, dy = c.y - f.y;
        red[t] = fminf(fmaxf(dx * dx, 1e-12f), 1e12f) + fminf(fmaxf(dy * dy, 1e-12f), 1e12f);
        for (int j = i + 1 + t; j < B; j += TPB)
            if (labs[j] == li) wsh = 0;           // benign race, same value
        __syncthreads();
        for (int s = 128; s; s >>= 1) { if (t < s) red[t] += red[t + s]; __syncthreads(); }
        if (t == 0) { rowLoss[i] = red[0]; winner[i] = wsh; }
    } else {
        copy_groups((const f4*)centers, (f4*)outAll, 1, K0E, (b - 512) * TPB + t, 1536 * TPB);
    }
}

// ---- k1: blocks 0-255 pairwise dist (32x32 tiles); blocks 256-2047 copy chunk1 ----
__global__ __launch_bounds__(TPB) void k1_pairdist(
    const float* __restrict__ centers, const float* __restrict__ cgbuf,
    float* __restrict__ dist, float* __restrict__ outAll)
{
    const int b = blockIdx.x, t = threadIdx.x;
    if (b < 256) {
        __shared__ float As[16][33];
        __shared__ float Bs[16][33];
        const int bi = b >> 4, bj = b & 15;
        const int tx = t & 15, ty = t >> 4;
        float a00 = 0.f, a01 = 0.f, a10 = 0.f, a11 = 0.f;
        for (int k0 = 0; k0 < D; k0 += 16) {
            #pragma unroll
            for (int it = 0; it < 2; ++it) {
                int idx = t + it * 256;              // 0..511
                int r = idx >> 4, kk = idx & 15;
                As[kk][r] = cgbuf[(size_t)(bi * 32 + r) * D + k0 + kk];
                Bs[kk][r] = cgbuf[(size_t)(bj * 32 + r) * D + k0 + kk];
            }
            __syncthreads();
            #pragma unroll
            for (int kk = 0; kk < 16; ++kk) {
                float x0 = As[kk][ty * 2], x1 = As[kk][ty * 2 + 1];
                float y0 = Bs[kk][tx * 2], y1 = Bs[kk][tx * 2 + 1];
                float d00 = x0 - y0, d01 = x0 - y1, d10 = x1 - y0, d11 = x1 - y1;
                a00 += d00 * d00; a01 += d01 * d01; a10 += d10 * d10; a11 += d11 * d11;
            }
            __syncthreads();
        }
        int r0 = bi * 32 + ty * 2, c0 = bj * 32 + tx * 2;
        dist[r0 * B + c0]           = sqrtf(a00);
        dist[r0 * B + c0 + 1]       = sqrtf(a01);
        dist[(r0 + 1) * B + c0]     = sqrtf(a10);
        dist[(r0 + 1) * B + c0 + 1] = sqrtf(a11);
    } else {
        copy_groups((const f4*)centers, (f4*)outAll, K0E, K1E, (b - 256) * TPB + t, 1792 * TPB);
    }
}

// ---- k2: blocks 0-511 masked softmax per row; blocks 512-2047 copy chunk2 ----
__global__ __launch_bounds__(TPB) void k2_softmax(
    const float* __restrict__ centers, const float* __restrict__ dist,
    const int* __restrict__ labels, float* __restrict__ Wm,
    float* __restrict__ rowS, float* __restrict__ rowCnt, float* __restrict__ outAll)
{
    const int b = blockIdx.x, t = threadIdx.x;
    if (b < B) {
        __shared__ float red[TPB];
        __shared__ int labs[B];
        labs[t] = labels[t]; labs[t + 256] = labels[t + 256];
        __syncthreads();
        const int i = b;
        const int li = labs[i];
        float d0 = dist[i * B + t], d1 = dist[i * B + t + 256];
        int m0 = (labs[t] != li) && (d0 <= MARGIN);
        int m1 = (labs[t + 256] != li) && (d1 <= MARGIN);
        red[t] = fmaxf(m0 ? d0 : 0.f, m1 ? d1 : 0.f); __syncthreads();
        for (int s = 128; s; s >>= 1) { if (t < s) red[t] = fmaxf(red[t], red[t + s]); __syncthreads(); }
        float maxd = red[0]; __syncthreads();
        float n0 = m0 ? expf(maxd - d0) : 0.f;
        float n1 = m1 ? expf(maxd - d1) : 0.f;
        red[t] = n0 + n1; __syncthreads();
        for (int s = 128; s; s >>= 1) { if (t < s) red[t] += red[t + s]; __syncthreads(); }
        float Z = red[0] + 1e-6f; __syncthreads();
        float invZ = 1.f / Z;
        Wm[i * B + t]       = n0 * invZ;
        Wm[i * B + t + 256] = n1 * invZ;
        red[t] = (float)(m0 + m1); __syncthreads();
        for (int s = 128; s; s >>= 1) { if (t < s) red[t] += red[t + s]; __syncthreads(); }
        if (t == 0) { rowS[i] = (Z - 1e-6f) * invZ; rowCnt[i] = red[0]; }
    } else {
        copy_groups((const f4*)centers, (f4*)outAll, K1E, K2E, (b - 512) * TPB + t, 1536 * TPB);
    }
}

// ---- k3: blocks 0-255 delta2 GEMM -> vals; block 256 loss + head/tail; 257-2047 copy chunk3 ----
__global__ __launch_bounds__(TPB) void k3_gemm(
    const float* __restrict__ features, const float* __restrict__ centers,
    const float* __restrict__ cgbuf, const float* __restrict__ Wm,
    const float* __restrict__ rowS, const float* __restrict__ rowCnt,
    const float* __restrict__ rowLoss, float* __restrict__ vals,
    float* __restrict__ out, float* __restrict__ outAll)
{
    const int b = blockIdx.x, t = threadIdx.x;
    float* outC = out + 1;
    if (b < 256) {
        __shared__ float red[TPB];
        __shared__ float As[16][33];
        __shared__ float Bs[16][33];
        __shared__ float fsh;
        // flag = (sum of all rowCnt >= 1), recomputed per block
        red[t] = rowCnt[t] + rowCnt[t + 256]; __syncthreads();
        for (int s = 128; s; s >>= 1) { if (t < s) red[t] += red[t + s]; __syncthreads(); }
        if (t == 0) fsh = (red[0] < 1.0f) ? 0.f : 1.f;
        __syncthreads();
        const float flagv = fsh;
        const int bi = b >> 4, bj = b & 15;
        const int tx = t & 15, ty = t >> 4;
        float a00 = 0.f, a01 = 0.f, a10 = 0.f, a11 = 0.f;
        for (int j0 = 0; j0 < B; j0 += 16) {
            #pragma unroll
            for (int it = 0; it < 2; ++it) {
                int idx = t + it * 256;
                int r = idx >> 4, jj = idx & 15;
                As[jj][r] = Wm[(size_t)(bi * 32 + r) * B + j0 + jj];
                int c = idx & 31, jj2 = idx >> 5;
                Bs[jj2][c] = cgbuf[(size_t)(j0 + jj2) * D + bj * 32 + c];
            }
            __syncthreads();
            #pragma unroll
            for (int kk = 0; kk < 16; ++kk) {
                float w0 = As[kk][ty * 2], w1 = As[kk][ty * 2 + 1];
                float c0 = Bs[kk][tx * 2], c1 = Bs[kk][tx * 2 + 1];
                a00 += w0 * c0; a01 += w0 * c1; a10 += w1 * c0; a11 += w1 * c1;
            }
            __syncthreads();
        }
        const int i0 = bi * 32 + ty * 2, i1 = i0 + 1;
        const int dcol = bj * 32 + tx * 2;
        float s0 = rowS[i0], s1 = rowS[i1];
        float c, f;
        c = cgbuf[(size_t)i0 * D + dcol];     f = features[(size_t)i0 * D + dcol];
        vals[(size_t)i0 * D + dcol]     = 0.5f * (c + f) - BETA * flagv * (s0 * c - a00);
        c = cgbuf[(size_t)i0 * D + dcol + 1]; f = features[(size_t)i0 * D + dcol + 1];
        vals[(size_t)i0 * D + dcol + 1] = 0.5f * (c + f) - BETA * flagv * (s0 * c - a01);
        c = cgbuf[(size_t)i1 * D + dcol];     f = features[(size_t)i1 * D + dcol];
        vals[(size_t)i1 * D + dcol]     = 0.5f * (c + f) - BETA * flagv * (s1 * c - a10);
        c = cgbuf[(size_t)i1 * D + dcol + 1]; f = features[(size_t)i1 * D + dcol + 1];
        vals[(size_t)i1 * D + dcol + 1] = 0.5f * (c + f) - BETA * flagv * (s1 * c - a11);
    } else if (b == 256) {
        __shared__ float red[TPB];
        red[t] = rowLoss[t] + rowLoss[t + 256]; __syncthreads();
        for (int s = 128; s; s >>= 1) { if (t < s) red[t] += red[t + s]; __syncthreads(); }
        if (t == 0) out[0] = red[0] * (1.0f / ((float)B * (float)D));
        // head (centers[0..2]) and tail (centers[NFLOAT-1]) not covered by the group grid.
        // k4's scatter (next kernel) overwrites these if they belong to winner rows.
        if (t == 1) { outC[0] = centers[0]; outC[1] = centers[1]; outC[2] = centers[2]; }
        if (t == 2) { outC[NFLOAT - 1] = centers[NFLOAT - 1]; }
    } else {
        copy_groups((const f4*)centers, (f4*)outAll, K2E, NG, (b - 257) * TPB + t, 1791 * TPB);
    }
}

// ---- k4: scatter winner rows from vals (runs after ALL copying complete) ----
__global__ __launch_bounds__(TPB) void k4_scatter(
    const float* __restrict__ vals, const int* __restrict__ labels,
    const int* __restrict__ winner, float* __restrict__ outC)
{
    const int b = blockIdx.x, t = threadIdx.x;
    const int i = b * 2 + (t >> 7);          // row 0..511
    const int dcol = (t & 127) * 4;
    if (!winner[i]) return;
    f4 v;
    __builtin_memcpy(&v, &vals[(size_t)i * D + dcol], 16);
    float* dst = outC + (size_t)labels[i] * D + dcol;   // 4B-aligned only
    __builtin_memcpy(dst, &v, 16);
}

extern "C" void kernel_launch(void* const* d_in, const int* in_sizes, int n_in,
                              void* d_out, int out_size, void* d_ws, size_t ws_size,
                              hipStream_t stream)
{
    const float* features = (const float*)d_in[0];
    const int*   labels   = (const int*)d_in[1];
    const float* centers  = (const float*)d_in[2];

    float* out  = (float*)d_out;     // out[0] = loss, out[1..] = new_centers
    float* outC = out + 1;

    char* ws = (char*)d_ws;
    float* cgbuf   = (float*)(ws);                 // 1 MB
    float* dist    = (float*)(ws + 1048576);       // 1 MB
    float* Wm      = (float*)(ws + 2097152);       // 1 MB
    float* vals    = (float*)(ws + 3145728);       // 1 MB
    float* rowLoss = (float*)(ws + 4194304);       // 2 KB
    float* rowS    = (float*)(ws + 4196352);       // 2 KB
    float* rowCnt  = (float*)(ws + 4198400);       // 2 KB
    int*   winner  = (int*)  (ws + 4200448);       // 2 KB

    k0_gather<<<2048, TPB, 0, stream>>>(centers, features, labels, cgbuf, rowLoss, winner, out);
    k1_pairdist<<<2048, TPB, 0, stream>>>(centers, cgbuf, dist, out);
    k2_softmax<<<2048, TPB, 0, stream>>>(centers, dist, labels, Wm, rowS, rowCnt, out);
    k3_gemm<<<2048, TPB, 0, stream>>>(features, centers, cgbuf, Wm, rowS, rowCnt,
                                      rowLoss, vals, out, out);
    k4_scatter<<<256, TPB, 0, stream>>>(vals, labels, winner, outC);
}